// Round 3
// baseline (110.295 us; speedup 1.0000x reference)
//
#include <hip/hip_runtime.h>
#include <hip/hip_bf16.h>

// ChannelMask: per-row exact quantile (linear interp) + >= mask.
// scale: [32, 192, 64, 64] f32 -> rows of n = 786432. pr: int scalar (device).
//
// R2 structure: hist1 (2048-bin, bits 31:21) -> compact candidates of the
// two target bins (ranks k, k+1) -> sel2 (2-level LDS select over candidates,
// exact order stats + lerp) -> mask. 3 data reads + 1 write, 5 launches.
// CAP=65536 per candidate list (worst-case normal-dist bin ~33K; pr=5 -> ~150).

typedef unsigned int uint32;

#define CAP 65536
#define NBIN1 2048

__device__ __forceinline__ uint32 fmap(uint32 b) {
    return (b & 0x80000000u) ? ~b : (b | 0x80000000u);
}
__device__ __forceinline__ float finv(uint32 u) {
    uint32 b = (u & 0x80000000u) ? (u & 0x7FFFFFFFu) : ~u;
    return __uint_as_float(b);
}

struct Sel { int found; uint32 bin; uint32 rem; };

// One wave (64 lanes, all active) selects bin containing rank `target` in
// hist[0..64*bpl). Exactly one lane returns found=1.
__device__ Sel wave_select(const uint32* __restrict__ hist, int bpl, uint32 target) {
    int lane = threadIdx.x & 63;
    uint32 s = 0;
    for (int j = 0; j < bpl; ++j) s += hist[lane * bpl + j];
    uint32 incl = s;
    for (int d = 1; d < 64; d <<= 1) {
        uint32 t = __shfl_up(incl, d, 64);
        if (lane >= d) incl += t;
    }
    uint32 excl = incl - s;
    Sel r; r.found = 0; r.bin = 0; r.rem = 0;
    if (target >= excl && target < excl + s) {
        uint32 rem = target - excl;
        for (int j = 0; j < bpl; ++j) {
            uint32 c = hist[lane * bpl + j];
            if (rem < c) { r.found = 1; r.bin = (uint32)(lane * bpl + j); r.rem = rem; break; }
            rem -= c;
        }
    }
    return r;
}

__device__ __forceinline__ void quant_params(int pr, int n, uint32* k, float* frac) {
    float qf = 1.0f - (float)pr * 0.1f;
    qf = fminf(fmaxf(qf, 0.f), 1.f);
    float virt = qf * (float)(n - 1);
    *k = (uint32)floorf(virt);
    *frac = virt - floorf(virt);
}

__global__ void __launch_bounds__(256) zero_k(uint32* __restrict__ ws, int nwords) {
    int i = blockIdx.x * 256 + threadIdx.x;
    if (i < nwords) ws[i] = 0;
}

__global__ void __launch_bounds__(256) hist1_k(const float* __restrict__ x,
                                               uint32* __restrict__ g1, int n4) {
    __shared__ uint32 h[4][NBIN1];
    int row = blockIdx.y;
    for (int i = threadIdx.x; i < 4 * NBIN1; i += 256) ((uint32*)h)[i] = 0;
    __syncthreads();
    const float4* p = (const float4*)x + (size_t)row * (size_t)n4;
    uint32* hw = h[(threadIdx.x >> 6) & 3];
    for (int i = blockIdx.x * 256 + threadIdx.x; i < n4; i += gridDim.x * 256) {
        float4 v = p[i];
        atomicAdd(&hw[fmap(__float_as_uint(v.x)) >> 21], 1u);
        atomicAdd(&hw[fmap(__float_as_uint(v.y)) >> 21], 1u);
        atomicAdd(&hw[fmap(__float_as_uint(v.z)) >> 21], 1u);
        atomicAdd(&hw[fmap(__float_as_uint(v.w)) >> 21], 1u);
    }
    __syncthreads();
    uint32* gr = g1 + (size_t)row * NBIN1;
    for (int i = threadIdx.x; i < NBIN1; i += 256) {
        uint32 s = h[0][i] + h[1][i] + h[2][i] + h[3][i];
        if (s) atomicAdd(&gr[i], s);
    }
}

// Each block: wave0 recomputes the level-0 select from g1 (L2-broadcast 8KB),
// then all threads stream the row, appending elems of target bins to cand lists.
__global__ void __launch_bounds__(256) compact_k(const float* __restrict__ x,
                                                 const uint32* __restrict__ g1,
                                                 const int* __restrict__ prp,
                                                 uint32* __restrict__ cnt,
                                                 uint32* __restrict__ cand,
                                                 int n4, int n) {
    __shared__ uint32 sBin[2];
    int row = blockIdx.y;
    if (threadIdx.x < 2) sBin[threadIdx.x] = 0xFFFFFFFFu;
    __syncthreads();
    if (threadIdx.x < 64) {
        int pr = *prp;
        uint32 k; float frac;
        quant_params(pr, n, &k, &frac);
#pragma unroll
        for (int t = 0; t < 2; ++t) {
            Sel r = wave_select(g1 + (size_t)row * NBIN1, NBIN1 / 64, k + (uint32)t);
            if (r.found) sBin[t] = r.bin;
        }
    }
    __syncthreads();
    uint32 bA = sBin[0], bB = sBin[1];
    uint32* cA = cand + (size_t)(row * 2 + 0) * CAP;
    uint32* cB = cand + (size_t)(row * 2 + 1) * CAP;
    const float4* p = (const float4*)x + (size_t)row * (size_t)n4;
    for (int i = blockIdx.x * 256 + threadIdx.x; i < n4; i += gridDim.x * 256) {
        float4 v = p[i];
        uint32 uu[4] = { fmap(__float_as_uint(v.x)), fmap(__float_as_uint(v.y)),
                         fmap(__float_as_uint(v.z)), fmap(__float_as_uint(v.w)) };
#pragma unroll
        for (int e = 0; e < 4; ++e) {
            uint32 hi = uu[e] >> 21;
            if (hi == bA) {
                uint32 idx = atomicAdd(&cnt[row * 2 + 0], 1u);
                if (idx < CAP) cA[idx] = uu[e];
            }
            if (hi == bB) {
                uint32 idx = atomicAdd(&cnt[row * 2 + 1], 1u);
                if (idx < CAP) cB[idx] = uu[e];
            }
        }
    }
}

// One block per row: for each target t, recompute level-0 select from g1, then
// 2-level LDS histogram select over the candidate list -> exact value; lerp.
__global__ void __launch_bounds__(256) sel2_k(const uint32* __restrict__ g1,
                                              const uint32* __restrict__ cnt,
                                              const uint32* __restrict__ cand,
                                              const int* __restrict__ prp,
                                              float* __restrict__ qarr, int n) {
    __shared__ uint32 h[NBIN1];
    __shared__ uint32 sc[4];   // bin0, rem0, mid, rem1
    __shared__ float svals[2];
    int row = blockIdx.x, tid = threadIdx.x;
    int pr = *prp;
    uint32 k; float frac;
    quant_params(pr, n, &k, &frac);
#pragma unroll
    for (int t = 0; t < 2; ++t) {
        if (tid == 0) { sc[0] = 0xFFFFFFFFu; svals[t] = 0.f; }
        __syncthreads();
        if (tid < 64) {
            Sel r = wave_select(g1 + (size_t)row * NBIN1, NBIN1 / 64, k + (uint32)t);
            if (r.found) { sc[0] = r.bin; sc[1] = r.rem; }
        }
        __syncthreads();
        uint32 b0 = sc[0];
        if (b0 != 0xFFFFFFFFu) {
            uint32 rem0 = sc[1];
            uint32 c = cnt[row * 2 + t]; if (c > CAP) c = CAP;
            const uint32* cl = cand + (size_t)(row * 2 + t) * CAP;
            // level A: bits 20:10
            for (int i = tid; i < NBIN1; i += 256) h[i] = 0;
            __syncthreads();
            for (int i = tid; i < (int)c; i += 256)
                atomicAdd(&h[(cl[i] >> 10) & 2047u], 1u);
            __syncthreads();
            if (tid < 64) {
                Sel r = wave_select(h, NBIN1 / 64, rem0);
                if (r.found) { sc[2] = r.bin; sc[3] = r.rem; }
            }
            __syncthreads();
            uint32 mid = sc[2], rem1 = sc[3];
            // level B: bits 9:0
            for (int i = tid; i < 1024; i += 256) h[i] = 0;
            __syncthreads();
            for (int i = tid; i < (int)c; i += 256) {
                uint32 u = cl[i];
                if (((u >> 10) & 2047u) == mid) atomicAdd(&h[u & 1023u], 1u);
            }
            __syncthreads();
            if (tid < 64) {
                Sel r = wave_select(h, 1024 / 64, rem1);
                if (r.found) {
                    uint32 uf = (b0 << 21) | (mid << 10) | r.bin;
                    svals[t] = finv(uf);
                }
            }
            __syncthreads();
        }
    }
    if (tid == 0) {
        double qd = (double)svals[0] * (1.0 - (double)frac) +
                    (double)svals[1] * (double)frac;
        qarr[row] = (float)qd;
    }
}

__global__ void __launch_bounds__(256) mask_k(const float4* __restrict__ x,
                                              const float* __restrict__ qarr,
                                              const int* __restrict__ prp,
                                              float4* __restrict__ out, int n4) {
    int row = blockIdx.y;
    int pr = *prp;
    const float4* p = x + (size_t)row * (size_t)n4;
    float4* o = out + (size_t)row * (size_t)n4;
    int stride = gridDim.x * 256;
    if (pr >= 10) {
        float4 one = make_float4(1.f, 1.f, 1.f, 1.f);
        for (int i = blockIdx.x * 256 + threadIdx.x; i < n4; i += stride) o[i] = one;
        return;
    }
    if (pr <= 0) {
        float4 zero = make_float4(0.f, 0.f, 0.f, 0.f);
        for (int i = blockIdx.x * 256 + threadIdx.x; i < n4; i += stride) o[i] = zero;
        return;
    }
    float q = qarr[row];
    for (int i = blockIdx.x * 256 + threadIdx.x; i < n4; i += stride) {
        float4 v = p[i];
        float4 r;
        r.x = (v.x >= q) ? 1.f : 0.f;
        r.y = (v.y >= q) ? 1.f : 0.f;
        r.z = (v.z >= q) ? 1.f : 0.f;
        r.w = (v.w >= q) ? 1.f : 0.f;
        o[i] = r;
    }
}

extern "C" void kernel_launch(void* const* d_in, const int* in_sizes, int n_in,
                              void* d_out, int out_size, void* d_ws, size_t ws_size,
                              hipStream_t stream) {
    const float* x = (const float*)d_in[0];
    const int* prp = (const int*)d_in[1];
    float* out = (float*)d_out;

    const int BS = 32;
    int total = in_sizes[0];     // 25165824
    int n = total / BS;          // 786432 per row
    int n4 = n / 4;              // 196608

    uint32* ws = (uint32*)d_ws;
    uint32* g1 = ws;                          // 32*2048 = 65536 words
    uint32* cnt = g1 + 32 * NBIN1;            // 64 words
    uint32* cand = cnt + 64;                  // 64 * CAP words (16 MiB)
    float* qarr = (float*)(cand + 64 * (size_t)CAP); // 32 words

    int zwords = 32 * NBIN1 + 64;             // g1 + cnt only
    zero_k<<<(zwords + 255) / 256, 256, 0, stream>>>(ws, zwords);

    hist1_k<<<dim3(48, BS), 256, 0, stream>>>(x, g1, n4);
    compact_k<<<dim3(48, BS), 256, 0, stream>>>(x, g1, prp, cnt, cand, n4, n);
    sel2_k<<<BS, 256, 0, stream>>>(g1, cnt, cand, prp, qarr, n);
    mask_k<<<dim3(96, BS), 256, 0, stream>>>((const float4*)x, qarr, prp, (float4*)out, n4);
}

// Round 4
// 80.032 us; speedup vs baseline: 1.3781x; 1.3781x over previous
//
#include <hip/hip_runtime.h>
#include <hip/hip_bf16.h>

// ChannelMask: per-row exact quantile (linear interp) + >= mask.
// scale: [32, 192, 64, 64] f32 -> rows of n = 786432. pr: int scalar (device).
//
// R3 structure (2 full reads + 1 full write, 4 launches):
//   hist1      : per-block non-atomic partial 2048-bin histograms (bits 31:21)
//   reduce_sel : sum partials, select level-0 bins for ranks k,k+1, zero cnt
//   maskcand   : fused mask-write + boundary-candidate compaction
//   fixup      : exact 2-level select over candidates -> q -> scatter-fix
// Mask rule: bin>bB -> 1, bin<bA -> 0, else compare vs q (exact order stats).

typedef unsigned int uint32;

#define NBIN1 2048
#define HBLK  48
#define CAP   65536

__device__ __forceinline__ uint32 fmap(uint32 b) {
    return (b & 0x80000000u) ? ~b : (b | 0x80000000u);
}
__device__ __forceinline__ float finv(uint32 u) {
    uint32 b = (u & 0x80000000u) ? (u & 0x7FFFFFFFu) : ~u;
    return __uint_as_float(b);
}

struct Sel { int found; uint32 bin; uint32 rem; };

// One wave (64 lanes, all active) selects bin containing rank `target` in
// hist[0..64*bpl). Exactly one lane returns found=1.
__device__ Sel wave_select(const uint32* hist, int bpl, uint32 target) {
    int lane = threadIdx.x & 63;
    uint32 s = 0;
    for (int j = 0; j < bpl; ++j) s += hist[lane * bpl + j];
    uint32 incl = s;
    for (int d = 1; d < 64; d <<= 1) {
        uint32 t = __shfl_up(incl, d, 64);
        if (lane >= d) incl += t;
    }
    uint32 excl = incl - s;
    Sel r; r.found = 0; r.bin = 0; r.rem = 0;
    if (target >= excl && target < excl + s) {
        uint32 rem = target - excl;
        for (int j = 0; j < bpl; ++j) {
            uint32 c = hist[lane * bpl + j];
            if (rem < c) { r.found = 1; r.bin = (uint32)(lane * bpl + j); r.rem = rem; break; }
            rem -= c;
        }
    }
    return r;
}

__device__ __forceinline__ void quant_params(int pr, int n, uint32* k, float* frac) {
    float qf = 1.0f - (float)pr * 0.1f;
    qf = fminf(fmaxf(qf, 0.f), 1.f);
    float virt = qf * (float)(n - 1);
    *k = (uint32)floorf(virt);
    *frac = virt - floorf(virt);
}

__global__ void __launch_bounds__(256) hist1_k(const float* __restrict__ x,
                                               uint32* __restrict__ g1p, int n4) {
    __shared__ uint32 h[4][NBIN1];
    int row = blockIdx.y;
    for (int i = threadIdx.x; i < 4 * NBIN1; i += 256) ((uint32*)h)[i] = 0;
    __syncthreads();
    const float4* p = (const float4*)x + (size_t)row * (size_t)n4;
    uint32* hw = h[(threadIdx.x >> 6) & 3];
    for (int i = blockIdx.x * 256 + threadIdx.x; i < n4; i += gridDim.x * 256) {
        float4 v = p[i];
        atomicAdd(&hw[fmap(__float_as_uint(v.x)) >> 21], 1u);
        atomicAdd(&hw[fmap(__float_as_uint(v.y)) >> 21], 1u);
        atomicAdd(&hw[fmap(__float_as_uint(v.z)) >> 21], 1u);
        atomicAdd(&hw[fmap(__float_as_uint(v.w)) >> 21], 1u);
    }
    __syncthreads();
    uint32* gp = g1p + ((size_t)row * HBLK + blockIdx.x) * NBIN1;
    for (int i = threadIdx.x; i < NBIN1; i += 256)
        gp[i] = h[0][i] + h[1][i] + h[2][i] + h[3][i];
}

// rowinfo layout per row: [bA, remA, bB, remB]
__global__ void __launch_bounds__(256) reduce_sel_k(const uint32* __restrict__ g1p,
                                                    const int* __restrict__ prp,
                                                    uint32* __restrict__ rowinfo,
                                                    uint32* __restrict__ cnt, int n) {
    __shared__ uint32 sh[NBIN1];
    int row = blockIdx.x, tid = threadIdx.x;
    const uint32* base = g1p + (size_t)row * HBLK * NBIN1;
    for (int i = tid; i < NBIN1; i += 256) {
        uint32 s = 0;
        for (int b = 0; b < HBLK; ++b) s += base[(size_t)b * NBIN1 + i];
        sh[i] = s;
    }
    if (tid == 0) cnt[row] = 0;
    __syncthreads();
    int pr = *prp;
    if (pr > 0 && pr < 10 && tid < 64) {
        uint32 k; float frac;
        quant_params(pr, n, &k, &frac);
#pragma unroll
        for (int t = 0; t < 2; ++t) {
            Sel r = wave_select(sh, NBIN1 / 64, k + (uint32)t);
            if (r.found) {
                rowinfo[row * 4 + 2 * t + 0] = r.bin;
                rowinfo[row * 4 + 2 * t + 1] = r.rem;
            }
        }
    }
}

__global__ void __launch_bounds__(256) maskcand_k(const float4* __restrict__ x,
                                                  const uint32* __restrict__ rowinfo,
                                                  const int* __restrict__ prp,
                                                  uint32* __restrict__ cnt,
                                                  uint32* __restrict__ candIdx,
                                                  uint32* __restrict__ candCode,
                                                  float4* __restrict__ out, int n4) {
    int row = blockIdx.y;
    int pr = *prp;
    const float4* p = x + (size_t)row * (size_t)n4;
    float4* o = out + (size_t)row * (size_t)n4;
    int stride = gridDim.x * 256;
    if (pr >= 10) {
        float4 one = make_float4(1.f, 1.f, 1.f, 1.f);
        for (int i = blockIdx.x * 256 + threadIdx.x; i < n4; i += stride) o[i] = one;
        return;
    }
    if (pr <= 0) {
        float4 zero = make_float4(0.f, 0.f, 0.f, 0.f);
        for (int i = blockIdx.x * 256 + threadIdx.x; i < n4; i += stride) o[i] = zero;
        return;
    }
    uint32 bA = rowinfo[row * 4 + 0];
    uint32 bB = rowinfo[row * 4 + 2];
    uint32 lo = bA << 21;
    uint32 hiIncl = (bB << 21) | 0x1FFFFFu;
    uint32* ci = candIdx + (size_t)row * CAP;
    uint32* cc = candCode + (size_t)row * CAP;
    for (int i = blockIdx.x * 256 + threadIdx.x; i < n4; i += stride) {
        float4 v = p[i];
        uint32 uu[4] = { fmap(__float_as_uint(v.x)), fmap(__float_as_uint(v.y)),
                         fmap(__float_as_uint(v.z)), fmap(__float_as_uint(v.w)) };
        float m[4];
#pragma unroll
        for (int e = 0; e < 4; ++e) {
            m[e] = (uu[e] > hiIncl) ? 1.f : 0.f;
            if (uu[e] >= lo && uu[e] <= hiIncl) {
                uint32 idx = atomicAdd(&cnt[row], 1u);
                if (idx < CAP) { ci[idx] = (uint32)(i * 4 + e); cc[idx] = uu[e]; }
                m[e] = 0.f;
            }
        }
        o[i] = make_float4(m[0], m[1], m[2], m[3]);
    }
}

__global__ void __launch_bounds__(256) fixup_k(const uint32* __restrict__ rowinfo,
                                               const uint32* __restrict__ cnt,
                                               const uint32* __restrict__ candIdx,
                                               const uint32* __restrict__ candCode,
                                               const int* __restrict__ prp,
                                               float* __restrict__ out, int n) {
    int pr = *prp;
    if (pr <= 0 || pr >= 10) return;
    __shared__ uint32 h[NBIN1];
    __shared__ uint32 sc[2];
    __shared__ float sval[2];
    int row = blockIdx.x, tid = threadIdx.x;
    uint32 c = cnt[row]; if (c > CAP) c = CAP;
    const uint32* cc = candCode + (size_t)row * CAP;
    const uint32* ci = candIdx + (size_t)row * CAP;
    uint32 k; float frac;
    quant_params(pr, n, &k, &frac);
#pragma unroll
    for (int t = 0; t < 2; ++t) {
        uint32 tb = rowinfo[row * 4 + 2 * t + 0];
        uint32 trem = rowinfo[row * 4 + 2 * t + 1];
        // level mid: bits 20:10 among candidates in bin tb
        for (int i = tid; i < NBIN1; i += 256) h[i] = 0;
        __syncthreads();
        for (int i = tid; i < (int)c; i += 256) {
            uint32 u = cc[i];
            if ((u >> 21) == tb) atomicAdd(&h[(u >> 10) & 2047u], 1u);
        }
        __syncthreads();
        if (tid < 64) {
            Sel r = wave_select(h, NBIN1 / 64, trem);
            if (r.found) { sc[0] = r.bin; sc[1] = r.rem; }
        }
        __syncthreads();
        uint32 mid = sc[0], rem1 = sc[1];
        // level low: bits 9:0
        for (int i = tid; i < 1024; i += 256) h[i] = 0;
        __syncthreads();
        for (int i = tid; i < (int)c; i += 256) {
            uint32 u = cc[i];
            if ((u >> 21) == tb && ((u >> 10) & 2047u) == mid)
                atomicAdd(&h[u & 1023u], 1u);
        }
        __syncthreads();
        if (tid < 64) {
            Sel r = wave_select(h, 1024 / 64, rem1);
            if (r.found) sval[t] = finv((tb << 21) | (mid << 10) | r.bin);
        }
        __syncthreads();
    }
    double qd = (double)sval[0] * (1.0 - (double)frac) + (double)sval[1] * (double)frac;
    float q = (float)qd;
    float* orow = out + (size_t)row * (size_t)n;
    for (int i = tid; i < (int)c; i += 256)
        orow[ci[i]] = (finv(cc[i]) >= q) ? 1.f : 0.f;
}

extern "C" void kernel_launch(void* const* d_in, const int* in_sizes, int n_in,
                              void* d_out, int out_size, void* d_ws, size_t ws_size,
                              hipStream_t stream) {
    const float* x = (const float*)d_in[0];
    const int* prp = (const int*)d_in[1];
    float* out = (float*)d_out;

    const int BS = 32;
    int total = in_sizes[0];     // 25165824
    int n = total / BS;          // 786432 per row
    int n4 = n / 4;              // 196608

    uint32* ws = (uint32*)d_ws;
    uint32* g1p = ws;                                  // 32*48*2048 = 3145728 words
    uint32* cnt = g1p + (size_t)32 * HBLK * NBIN1;     // 32
    uint32* rowinfo = cnt + 32;                        // 128
    uint32* candIdx = rowinfo + 128;                   // 32*CAP
    uint32* candCode = candIdx + (size_t)32 * CAP;     // 32*CAP

    hist1_k<<<dim3(HBLK, BS), 256, 0, stream>>>(x, g1p, n4);
    reduce_sel_k<<<BS, 256, 0, stream>>>(g1p, prp, rowinfo, cnt, n);
    maskcand_k<<<dim3(96, BS), 256, 0, stream>>>((const float4*)x, rowinfo, prp, cnt,
                                                 candIdx, candCode, (float4*)out, n4);
    fixup_k<<<BS, 256, 0, stream>>>(rowinfo, cnt, candIdx, candCode, prp, out, n);
}